// Round 1
// baseline (439.624 us; speedup 1.0000x reference)
//
#include <hip/hip_runtime.h>

#define BATCH 128
#define NV (BATCH / 4)  // 32 float4 per row; 32 lanes cooperate on one row

__global__ __launch_bounds__(256) void ProdLayer_fwd(
    const float4* __restrict__ node4,   // node_mars as float4 rows [NUM_INPUT_NODES][32]
    const int*    __restrict__ nids,    // [num_nodes] output row ids (int32 per harness)
    const int*    __restrict__ cids,    // [num_nodes][2] child row ids
    float4*       __restrict__ out4,    // element_mars as float4 rows [NUM_ELS][32]
    int num_nodes)
{
    // Row 0 is the reserved dummy row: reference leaves it at element_mars'
    // initial value (zeros). d_out is poisoned 0xAA, so write zeros explicitly.
    if (blockIdx.x == 0 && threadIdx.x < NV) {
        out4[threadIdx.x] = make_float4(0.f, 0.f, 0.f, 0.f);
    }

    const int total  = num_nodes * NV;                    // 8,388,608 — fits int32
    const int stride = gridDim.x * blockDim.x;
    for (int idx = blockIdx.x * blockDim.x + threadIdx.x; idx < total; idx += stride) {
        const int n = idx >> 5;        // node index
        const int t = idx & 31;        // float4 slot within the row
        const int o  = nids[n];        // broadcast load (same addr across 32 lanes)
        const int c0 = cids[2 * n];
        const int c1 = cids[2 * n + 1];
        const float4 a = node4[c0 * NV + t];
        const float4 b = node4[c1 * NV + t];
        out4[o * NV + t] = make_float4(a.x + b.x, a.y + b.y, a.z + b.z, a.w + b.w);
    }
}

extern "C" void kernel_launch(void* const* d_in, const int* in_sizes, int n_in,
                              void* d_out, int out_size, void* d_ws, size_t ws_size,
                              hipStream_t stream) {
    const float4* node4 = (const float4*)d_in[0];
    // d_in[1] = element_mars input (all zeros) — only row 0 survives into the
    // output, and it is zero, so we write zeros directly instead of copying.
    const int* nids = (const int*)d_in[2];
    const int* cids = (const int*)d_in[3];
    float4* out4 = (float4*)d_out;

    const int num_nodes = in_sizes[2];  // 262144

    const int block = 256;
    const int grid  = 2048;             // grid-stride; memory-bound cap (G11)
    ProdLayer_fwd<<<grid, block, 0, stream>>>(node4, nids, cids, out4, num_nodes);
}